// Round 1
// baseline (93.384 us; speedup 1.0000x reference)
//
#include <hip/hip_runtime.h>

// SimpleJoinModel: equi-join on integer-valued fp32 key columns.
// left: (N_LEFT, 256) f32, right: (N_RIGHT, 256) f32.
// Keys are permutations of 0..N-1 stored as exact fp32 integers.
//
// SCATTER formulation (v2): instead of gathering random left rows behind a
// key->table->gather dependent-load chain, we invert the RIGHT keys
// (rtable[rkey[i]] = i) and stream left rows sequentially, scattering each
// to its output slot. All reads are sequential/coalesced and issue with no
// dependence on the table lookup; the only random access is a full-line
// 1 KB store, which is latency-insensitive (fire-and-forget).

#define DCOLS 256   // feature dim of each input
#define OCOLS 512   // output row width

typedef float f4 __attribute__((ext_vector_type(4)));

// Invert the right-key permutation: rtable[key(right_i)] = i.
__global__ void build_rtable_kernel(const float* __restrict__ right,
                                    const int* __restrict__ right_on_p,
                                    int* __restrict__ rtable,
                                    int n_right, int tsize) {
    int i = blockIdx.x * blockDim.x + threadIdx.x;
    if (i >= n_right) return;
    int k = (int)right[(size_t)i * DCOLS + right_on_p[0]];
    if (k >= 0 && k < tsize) rtable[k] = i;
}

// One wave (64 lanes) per row index r. Each lane moves one float4 per half.
//  - right half: stream right row r -> out[r][256:512]   (pure streaming)
//  - left  half: stream left  row r, extract its key from the loaded
//    fragment via __shfl, look up dest = rtable[key], scatter-store the
//    row to out[dest][0:256]. The 1 KB load never waits on the table.
__global__ void scatter_join_kernel(const float* __restrict__ left,
                                    const float* __restrict__ right,
                                    const int* __restrict__ left_on_p,
                                    const int* __restrict__ rtable,
                                    float* __restrict__ out,
                                    int n_left, int n_right, int tsize) {
    int gtid = blockIdx.x * blockDim.x + threadIdx.x;
    int row  = gtid >> 6;          // wave index == row index
    int lane = threadIdx.x & 63;
    int lon  = left_on_p[0];       // same line for all waves -> L2-hot

    // Right half: fully streaming copy, independent of everything else.
    if (row < n_right) {
        f4 rv = __builtin_nontemporal_load(
                    (const f4*)(right + (size_t)row * DCOLS) + lane);
        __builtin_nontemporal_store(rv,
                    (f4*)(out + (size_t)row * OCOLS + DCOLS) + lane);
    }

    // Left half: streaming read, random (but full-line) scatter write.
    if (row < n_left) {
        f4 lv = __builtin_nontemporal_load(
                    (const f4*)(left + (size_t)row * DCOLS) + lane);
        // Key lives at column `lon` == lane (lon>>2), component (lon&3) of
        // the fragment we already loaded — no separate key load.
        float kf = ((const float*)&lv)[lon & 3];
        float kb = __shfl(kf, lon >> 2, 64);
        int   k  = (int)kb;
        int dest = (k >= 0 && k < tsize) ? rtable[k] : -1;
        if (dest >= 0 && dest < n_right)
            __builtin_nontemporal_store(lv,
                        (f4*)(out + (size_t)dest * OCOLS) + lane);
    }
}

extern "C" void kernel_launch(void* const* d_in, const int* in_sizes, int n_in,
                              void* d_out, int out_size, void* d_ws, size_t ws_size,
                              hipStream_t stream) {
    const float* left     = (const float*)d_in[0];
    const float* right    = (const float*)d_in[1];
    const int*   left_on  = (const int*)d_in[2];   // 1-element scalar array
    const int*   right_on = (const int*)d_in[3];   // 1-element scalar array
    float*       out      = (float*)d_out;

    int n_left  = in_sizes[0] / DCOLS;
    int n_right = in_sizes[1] / DCOLS;
    int tsize   = n_left > n_right ? n_left : n_right;

    int* rtable = (int*)d_ws;   // tsize ints; every slot that is read is
                                // written first (keys are permutations)

    {
        // Small latency-bound kernel: spread waves across CUs.
        int block = 64;
        int grid  = (n_right + block - 1) / block;
        build_rtable_kernel<<<grid, block, 0, stream>>>(right, right_on,
                                                        rtable, n_right, tsize);
    }
    {
        int rows = n_left > n_right ? n_left : n_right;
        int block = 256;                       // 4 waves -> 4 rows per block
        int rows_per_block = block / 64;
        int grid = (rows + rows_per_block - 1) / rows_per_block;
        scatter_join_kernel<<<grid, block, 0, stream>>>(left, right, left_on,
                                                        rtable, out,
                                                        n_left, n_right, tsize);
    }
}

// Round 2
// 90.943 us; speedup vs baseline: 1.0268x; 1.0268x over previous
//
#include <hip/hip_runtime.h>

// SimpleJoinModel: equi-join on integer-valued fp32 key columns.
// left: (N_LEFT, 256) f32, right: (N_RIGHT, 256) f32.
// Keys left[:,left_on] and right[:,right_on] are permutations of 0..N-1
// (exact fp32 integers), so an inverse-permutation table in d_ws gives O(1)
// lookup. Output row i = [left[table[key(right_i)]], right_i]  (512 f32).
//
// v3 (gather, polished): gather formulation re-established as the best
// measured variant (90.4 vs scatter's 93.4 — random 1 KB reads are served
// by the 256 MB Infinity Cache; random writes are not). Polish:
//  - right-half streaming load issued BEFORE the key->table->gather
//    dependent chain, so it is in flight while the chain resolves
//  - key extracted from the already-loaded right fragment via __shfl
//    (no separate key-load transaction)
//  - NT hints on single-use streams (right read, out writes)
//  - build kernel: 1 wave/CU across 256 CUs for its stride-1KB key loads

#define DCOLS 256   // feature dim of each input
#define OCOLS 512   // output row width

typedef float f4 __attribute__((ext_vector_type(4)));

// Invert the left-key permutation: table[key(left_j)] = j.
// Key loads are stride-1KB (one 128B line per lane) -> latency-bound;
// spread as 1 wave per CU for maximum memory-level parallelism.
__global__ void build_table_kernel(const float* __restrict__ left,
                                   const int* __restrict__ left_on_p,
                                   int* __restrict__ table,
                                   int n_left) {
    int j = blockIdx.x * blockDim.x + threadIdx.x;
    if (j >= n_left) return;
    int key = (int)left[(size_t)j * DCOLS + left_on_p[0]];
    if (key >= 0 && key < n_left) table[key] = j;
}

// One wave (64 lanes) per output row. Each lane moves one float4 per half:
// 64 lanes * 16 B = 1024 B = one 256-float half-row per vector instruction.
__global__ void join_kernel(const float* __restrict__ left,
                            const float* __restrict__ right,
                            const int* __restrict__ right_on_p,
                            const int* __restrict__ table,
                            float* __restrict__ out,
                            int n_right) {
    int gtid = blockIdx.x * blockDim.x + threadIdx.x;
    int row  = gtid >> 6;          // wave index == output row
    int lane = threadIdx.x & 63;
    if (row >= n_right) return;

    int ron = right_on_p[0];       // same line for all waves -> L2-hot

    // Independent streaming load of the right half — issued first so it is
    // in flight while the key->table->gather chain resolves.
    f4 rv = __builtin_nontemporal_load(
                (const f4*)(right + (size_t)row * DCOLS) + lane);

    // Key lives at column `ron` == lane (ron>>2), component (ron&3) of the
    // fragment we already loaded — extract via shfl, no extra load.
    float kf = ((const float*)&rv)[ron & 3];
    float kb = __shfl(kf, ron >> 2, 64);
    int   k  = (int)kb;
    int   j  = table[k];           // 4B random read, L2/L3-resident table

    // Random 1 KB gather of the matching left row. left (16.8 MB) is
    // L3-resident, so these reads are served by Infinity Cache.
    f4 lv = *((const f4*)(left + (size_t)j * DCOLS) + lane);

    f4* o = (f4*)(out + (size_t)row * OCOLS);
    __builtin_nontemporal_store(lv, o + lane);        // cols   0..255
    __builtin_nontemporal_store(rv, o + lane + 64);   // cols 256..511
}

extern "C" void kernel_launch(void* const* d_in, const int* in_sizes, int n_in,
                              void* d_out, int out_size, void* d_ws, size_t ws_size,
                              hipStream_t stream) {
    const float* left     = (const float*)d_in[0];
    const float* right    = (const float*)d_in[1];
    const int*   left_on  = (const int*)d_in[2];   // 1-element scalar array
    const int*   right_on = (const int*)d_in[3];   // 1-element scalar array
    float*       out      = (float*)d_out;

    int n_left  = in_sizes[0] / DCOLS;
    int n_right = in_sizes[1] / DCOLS;

    int* table = (int*)d_ws;   // n_left ints; every slot read by join is
                               // written first (keys are a permutation)

    {
        // 64-thread blocks -> 256 blocks -> 1 wave on each of the 256 CUs.
        int block = 64;
        int grid  = (n_left + block - 1) / block;
        build_table_kernel<<<grid, block, 0, stream>>>(left, left_on,
                                                       table, n_left);
    }
    {
        int block = 256;                       // 4 waves -> 4 rows per block
        int rows_per_block = block / 64;
        int grid = (n_right + rows_per_block - 1) / rows_per_block;
        join_kernel<<<grid, block, 0, stream>>>(left, right, right_on,
                                                table, out, n_right);
    }
}